// Round 5
// baseline (626.468 us; speedup 1.0000x reference)
//
#include <hip/hip_runtime.h>
#include <hip/hip_bf16.h>

// Grouped GEMM: out[n,g,k] = sum_d x[n*8+g, d] * W[g, k, d]
// Round 5 structure: trade intra-block pipelining for inter-block TLP.
//  1) cvt_w: W f32 -> bf16 image in d_ws, tiled [g][jt:8][kt:16][128r][64k]
//     in swizzled LDS-image byte order (linear global_load_lds dest).
//  2) gemm: 128x128 tile, BK=64, 4 waves, ~4 blocks/CU (LDS 32 KiB only).
//     A-fragments loaded DIRECTLY from global f32 + cvt_pk (lane-local
//     contiguous; no LDS round-trip). B via global_load_lds from image,
//     double-buffered, ONE vmcnt(0)+barrier per K-tile (DMA a tile ahead).

namespace {

constexpr int NG   = 8;
constexpr int DIN  = 1024;
constexpr int DOUT = 1024;
constexpr int BM   = 128;
constexpr int BN   = 128;
constexpr int BK   = 64;
constexpr int NKT  = DIN / BK;            // 16
constexpr int ROWB = BK * 2;              // 128 B per LDS row
constexpr int BTILE = BN * ROWB;          // 16 KiB per B tile
constexpr int JTN  = DOUT / BN;           // 8 col panels
constexpr size_t WSB_BYTES = (size_t)NG * JTN * NKT * BTILE;  // 16.78 MB

typedef __attribute__((ext_vector_type(8))) short bf16x8;
typedef __attribute__((ext_vector_type(4))) float f32x4;

__device__ __forceinline__ bf16x8 pack_bf16x8(f32x4 lo, f32x4 hi) {
  union { __hip_bfloat162 h2[4]; bf16x8 v; } p;
  p.h2[0] = __float22bfloat162_rn(make_float2(lo.x, lo.y));
  p.h2[1] = __float22bfloat162_rn(make_float2(lo.z, lo.w));
  p.h2[2] = __float22bfloat162_rn(make_float2(hi.x, hi.y));
  p.h2[3] = __float22bfloat162_rn(make_float2(hi.z, hi.w));
  return p.v;
}

__device__ __forceinline__ void glds16(const void* g, void* l) {
  __builtin_amdgcn_global_load_lds(
      (const __attribute__((address_space(1))) unsigned int*)g,
      (__attribute__((address_space(3))) unsigned int*)l, 16, 0, 0);
}

#define FENCE() asm volatile("" ::: "memory")
#define BAR()   do { FENCE(); __builtin_amdgcn_s_barrier(); FENCE(); } while (0)
#define LGKM0() asm volatile("s_waitcnt lgkmcnt(0)" ::: "memory")
#define VM0()   asm volatile("s_waitcnt vmcnt(0)" ::: "memory")
#define MFMA_(a, b, c) __builtin_amdgcn_mfma_f32_16x16x32_bf16((a), (b), (c), 0, 0, 0)

// ---------------- kernel 1: W f32 -> bf16 swizzled-tile image --------------
__global__ __launch_bounds__(256)
void cvt_w_kernel(const float* __restrict__ W, char* __restrict__ wsB) {
  const int q    = (int)blockIdx.x * 256 + (int)threadIdx.x;  // u32 index
  const int tile = q >> 12;            // [g*8+jt]*16+kt   (4096 u32 / tile)
  const int q12  = q & 4095;
  const int r    = q12 >> 5;           // LDS row 0..127
  const int cp   = q12 & 31;           // col-pair 0..31 (bf16 cols 2cp,2cp+1)
  const int g    = tile >> 7;
  const int jt   = (tile >> 4) & 7;
  const int kt   = tile & 15;

  const float2 s = *(const float2*)(
      W + ((size_t)(g * DOUT + jt * BN + r)) * DIN + kt * 64 + 2 * cp);
  union { __hip_bfloat162 h; unsigned u; } pk;
  pk.h = __float22bfloat162_rn(make_float2(s.x, s.y));

  const int swz = (r & 7) << 4;
  const int dstByte = r * ROWB + (((cp >> 2) * 16) ^ swz) + (cp & 3) * 4;
  *(unsigned*)(wsB + (size_t)tile * BTILE + dstByte) = pk.u;
}

// ---------------- kernel 2: grouped GEMM -----------------------------------
template <bool WSB>
__global__ __launch_bounds__(256, 4)
void grouped_gemm_tlp(const float* __restrict__ X,
                      const float* __restrict__ W,
                      const char* __restrict__ wsB,
                      float* __restrict__ O) {
  __shared__ __align__(16) char smB[2][BTILE];   // 32 KiB total

  // ---- block mapping: group == XCD (4096 blocks, 512/XCD), bijective
  const int bid = (int)blockIdx.x;
  const int swz = (bid & 7) * 512 + (bid >> 3);
  const int jt = swz & 7;                  // col panel [0,8)  fastest: A reuse
  const int it = (swz >> 3) & 63;          // row tile  [0,64)
  const int g  = swz >> 9;                 // group     [0,8)  == XCD

  const int n0 = it * BM;
  const int c0 = jt * BN;

  const int tid  = (int)threadIdx.x;
  const int lane = tid & 63;
  const int wid  = tid >> 6;               // 4 waves: 2(M) x 2(N)
  const int wr   = wid >> 1;
  const int wc   = wid & 1;

  const int fr = lane & 15;
  const int fq = lane >> 4;

  // A: direct-from-global fragment base. row(m) = n0 + wr*64 + m*16 + fr,
  // k(ks) = kt*64 + ks*32 + fq*8. X row stride = NG*DIN floats.
  const float* Abase =
      X + ((size_t)(n0 + wr * 64 + fr) * NG + g) * DIN + fq * 8;
  constexpr size_t AMSTR = (size_t)16 * NG * DIN;   // +16 rows per m

  // B image stream (WSB) or raw W (fallback)
  const char* BgT = wsB + (size_t)((g * JTN + jt) * NKT) * BTILE;
  const int bOff = tid * 16;               // 256 thr * 16 B = 4 KiB per pass

  // fallback B reg-staging map: 16 lanes x f32x4 = 64 cols; 16 rows/pass
  const int s_lane = tid & 15;
  const int s_row  = tid >> 4;
  const float* Bg = W + (size_t)g * DOUT * DIN + (size_t)(c0 + s_row) * DIN
                      + s_lane * 4;
  constexpr size_t BSTR = (size_t)16 * DIN;
  const int wb0 = s_row * ROWB + ((s_lane * 8) ^ ((s_row & 7) << 4));

  // B fragment LDS addressing (XOR involution matches image/write side)
  const int swzm  = (fr & 7) << 4;
  const int colx0 = (fq * 16) ^ swzm;          // ks=0
  const int colx1 = (64 + fq * 16) ^ swzm;     // ks=1
  const int bRow0 = (wc * 64 + fr) * ROWB;

  f32x4 acc[4][4];
#pragma unroll
  for (int m = 0; m < 4; ++m)
#pragma unroll
    for (int n = 0; n < 4; ++n) acc[m][n] = (f32x4){0.f, 0.f, 0.f, 0.f};

  // ---- prologue: B tile 0 into buffer 0
  if (WSB) {
#pragma unroll
    for (int p = 0; p < 4; ++p)
      glds16(BgT + bOff + p * 4096, smB[0] + bOff + p * 4096);
    VM0();
  } else {
    f32x4 bS[8];
#pragma unroll
    for (int p = 0; p < 8; ++p) bS[p] = *(const f32x4*)(Bg + p * BSTR);
#pragma unroll
    for (int p = 0; p < 4; ++p)
      *(bf16x8*)(smB[0] + wb0 + p * 2048) = pack_bf16x8(bS[2*p], bS[2*p+1]);
    LGKM0();
  }
  BAR();

#pragma unroll 2
  for (int t = 0; t < NKT; ++t) {
    char* const cB = smB[t & 1];
    char* const nB = smB[(t & 1) ^ 1];
    const bool stage = (t + 1) < NKT;

    // issue next B tile a full K-tile ahead (prev barrier made nB safe)
    f32x4 bS[8];
    if (stage) {
      if (WSB) {
        const char* Bn = BgT + (size_t)(t + 1) * BTILE;
#pragma unroll
        for (int p = 0; p < 4; ++p)
          glds16(Bn + bOff + p * 4096, nB + bOff + p * 4096);
      } else {
        const float* Bn = Bg + (size_t)(t + 1) * BK;
#pragma unroll
        for (int p = 0; p < 8; ++p) bS[p] = *(const f32x4*)(Bn + p * BSTR);
      }
    }

    // B fragments for this tile (8 x ds_read_b128; compiler counts lgkm)
    bf16x8 bfr[4][2];
#pragma unroll
    for (int n = 0; n < 4; ++n) {
      bfr[n][0] = *(const bf16x8*)(cB + bRow0 + n * 2048 + colx0);
      bfr[n][1] = *(const bf16x8*)(cB + bRow0 + n * 2048 + colx1);
    }

    // A fragments straight from global (f32 -> cvt_pk -> MFMA)
    const float* At = Abase + (size_t)t * BK;
#pragma unroll
    for (int m = 0; m < 4; ++m) {
      const float* Am = At + (size_t)m * AMSTR;
      f32x4 a0lo = *(const f32x4*)(Am);
      f32x4 a0hi = *(const f32x4*)(Am + 4);
      f32x4 a1lo = *(const f32x4*)(Am + 32);
      f32x4 a1hi = *(const f32x4*)(Am + 36);
      bf16x8 a0 = pack_bf16x8(a0lo, a0hi);
      bf16x8 a1 = pack_bf16x8(a1lo, a1hi);
#pragma unroll
      for (int n = 0; n < 4; ++n) {
        acc[m][n] = MFMA_(a0, bfr[n][0], acc[m][n]);
        acc[m][n] = MFMA_(a1, bfr[n][1], acc[m][n]);
      }
    }

    // fallback: convert + write next B tile after compute
    if (!WSB && stage) {
#pragma unroll
      for (int p = 0; p < 4; ++p)
        *(bf16x8*)(nB + wb0 + p * 2048) = pack_bf16x8(bS[2*p], bS[2*p+1]);
    }

    // tile boundary: own DMA/writes drained, then block-wide publish
    LGKM0();
    if (WSB && stage) { VM0(); }
    BAR();
  }

  // ---- epilogue: C/D layout col = lane&15, row = (lane>>4)*4 + reg (m89)
#pragma unroll
  for (int m = 0; m < 4; ++m) {
#pragma unroll
    for (int r = 0; r < 4; ++r) {
      const int row = wr * 64 + m * 16 + fq * 4 + r;
      float* orow = O + ((size_t)(n0 + row) * NG + g) * DOUT + c0 + wc * 64;
#pragma unroll
      for (int n = 0; n < 4; ++n) {
        orow[n * 16 + fr] = acc[m][n][r];
      }
    }
  }
}

} // namespace

extern "C" void kernel_launch(void* const* d_in, const int* in_sizes, int n_in,
                              void* d_out, int out_size, void* d_ws, size_t ws_size,
                              hipStream_t stream) {
  (void)n_in; (void)out_size;
  const float* X = (const float*)d_in[0];
  const float* W = (const float*)d_in[1];
  float* O = (float*)d_out;

  const int tokens_total = in_sizes[0] / DIN;            // 65536
  const int ntok_per_g   = tokens_total / NG;            // 8192
  const int grid = NG * (ntok_per_g / BM) * (DOUT / BN); // 4096

  if (ws_size >= WSB_BYTES) {
    const int cvt_grid = (int)(WSB_BYTES / 4 / 256);     // 16384
    cvt_w_kernel<<<dim3(cvt_grid), dim3(256), 0, stream>>>(W, (char*)d_ws);
    grouped_gemm_tlp<true><<<dim3(grid), dim3(256), 0, stream>>>(
        X, W, (const char*)d_ws, O);
  } else {
    grouped_gemm_tlp<false><<<dim3(grid), dim3(256), 0, stream>>>(
        X, W, nullptr, O);
  }
}

// Round 6
// 273.703 us; speedup vs baseline: 2.2889x; 2.2889x over previous
//
#include <hip/hip_runtime.h>
#include <hip/hip_bf16.h>

// Grouped GEMM: out[n,g,k] = sum_d x[n*8+g, d] * W[g, k, d]
// Round 6: ALL fp32->bf16 conversion moved to pre-passes that write swizzled
// LDS-image tiles into d_ws; the GEMM stages A and B purely with
// global_load_lds (linear dest, pre-swizzled source = rule #21 both-sides).
//  - cvt_x: X -> A-image [g][it:32][kt:16] tiles of [256r][64k] bf16 (128 MB)
//  - cvt_w: W -> B-image [g][jt:4][kt:16] tiles of [256r][64k] bf16 (16.8 MB)
//  - gemm_full: 256x256, BK=64, 8 waves, 4 phases/K-tile (T3), counted vmcnt
//    (T4: single VM0 per tile, 4-phase-deep DMA), setprio (T5), XOR-swizzle
//    reads (T2), group-per-XCD (T1).
// Fallbacks: ws >= 16.8 MB -> round-4 kernel (B image, A reg-staged);
//            else fully reg-staged.

namespace {

constexpr int NG   = 8;
constexpr int DIN  = 1024;
constexpr int DOUT = 1024;
constexpr int BM   = 256;
constexpr int BN   = 256;
constexpr int BK   = 64;
constexpr int NKT  = DIN / BK;            // 16
constexpr int ROWB = BK * 2;              // 128 B per LDS row
constexpr int LDS_TILE  = BM * ROWB;      // 32 KiB per tile buffer
constexpr int LDS_BYTES = 4 * LDS_TILE;   // 128 KiB: A0,A1,B0,B1
constexpr int JTN  = DOUT / BN;           // 4 col panels
constexpr int ITN  = 32;                  // row tiles per group (8192/256)
constexpr size_t WSB_BYTES = (size_t)NG * JTN * NKT * LDS_TILE;  // 16.78 MB
constexpr size_t WSA_BYTES = (size_t)NG * ITN * NKT * LDS_TILE;  // 134.2 MB
constexpr size_t WSF_BYTES = WSA_BYTES + WSB_BYTES;              // 151.0 MB

typedef __attribute__((ext_vector_type(8))) short bf16x8;
typedef __attribute__((ext_vector_type(4))) float f32x4;

__device__ __forceinline__ uint2 pack_bf16x4(f32x4 v) {
  union { __hip_bfloat162 h2[2]; uint2 u; } p;
  p.h2[0] = __float22bfloat162_rn(make_float2(v.x, v.y));
  p.h2[1] = __float22bfloat162_rn(make_float2(v.z, v.w));
  return p.u;
}

__device__ __forceinline__ bf16x8 pack_bf16x8v(f32x4 lo, f32x4 hi) {
  union { __hip_bfloat162 h2[4]; bf16x8 v; } p;
  p.h2[0] = __float22bfloat162_rn(make_float2(lo.x, lo.y));
  p.h2[1] = __float22bfloat162_rn(make_float2(lo.z, lo.w));
  p.h2[2] = __float22bfloat162_rn(make_float2(hi.x, hi.y));
  p.h2[3] = __float22bfloat162_rn(make_float2(hi.z, hi.w));
  return p.v;
}

__device__ __forceinline__ void glds16(const void* g, void* l) {
  __builtin_amdgcn_global_load_lds(
      (const __attribute__((address_space(1))) unsigned int*)g,
      (__attribute__((address_space(3))) unsigned int*)l, 16, 0, 0);
}

#define FENCE() asm volatile("" ::: "memory")
#define BAR()   do { FENCE(); __builtin_amdgcn_s_barrier(); FENCE(); } while (0)
#define LGKM0() asm volatile("s_waitcnt lgkmcnt(0)" ::: "memory")
#define VM0()   asm volatile("s_waitcnt vmcnt(0)" ::: "memory")
#define MFMA_(a, b, c) __builtin_amdgcn_mfma_f32_16x16x32_bf16((a), (b), (c), 0, 0, 0)

// ---------------- cvt_w: W f32 -> bf16 swizzled B-image --------------------
__global__ __launch_bounds__(256)
void cvt_w_kernel(const float* __restrict__ W, char* __restrict__ wsB) {
  const int q    = (int)blockIdx.x * 256 + (int)threadIdx.x;  // u32 index
  const int tile = q >> 13;            // [g*4+jt]*16+kt (8192 u32 per tile)
  const int q13  = q & 8191;
  const int r    = q13 >> 5;           // LDS row 0..255
  const int cp   = q13 & 31;           // col-pair (bf16 cols 2cp,2cp+1)
  const int g    = tile >> 6;
  const int jt   = (tile >> 4) & 3;
  const int kt   = tile & 15;

  const float2 s = *(const float2*)(
      W + ((size_t)(g * DOUT + jt * BN + r)) * DIN + kt * 64 + 2 * cp);
  union { __hip_bfloat162 h; unsigned u; } pk;
  pk.h = __float22bfloat162_rn(make_float2(s.x, s.y));

  const int swz = (r & 7) << 4;
  const int dstByte = r * ROWB + (((cp >> 2) * 16) ^ swz) + (cp & 3) * 4;
  *(unsigned*)(wsB + (size_t)tile * LDS_TILE + dstByte) = pk.u;
}

// ---------------- cvt_x: X f32 -> bf16 swizzled A-image --------------------
// dest chunk (tile, r, w) holds source k-chunk (w ^ (r&7)) so that the
// GEMM's XOR-swizzled ds_read recovers the original column.
__global__ __launch_bounds__(256)
void cvt_x_kernel(const float* __restrict__ X, char* __restrict__ wsA) {
  const int q    = (int)blockIdx.x * 256 + (int)threadIdx.x;  // 16B-chunk id
  const int tile = q >> 11;            // [g*32+it]*16+kt (2048 chunks/tile)
  const int c    = q & 2047;
  const int r    = c >> 3;             // LDS row 0..255
  const int w    = c & 7;              // chunk-in-row 0..7 (8 bf16 each)
  const int g    = tile >> 9;
  const int it   = (tile >> 4) & 31;
  const int kt   = tile & 15;

  const float* src = X + ((size_t)(it * BM + r) * NG + g) * DIN
                       + kt * 64 + (w ^ (r & 7)) * 8;
  f32x4 lo = *(const f32x4*)(src);
  f32x4 hi = *(const f32x4*)(src + 4);
  *(bf16x8*)(wsA + (size_t)q * 16) = pack_bf16x8v(lo, hi);
}

// ---------------- phase macro (shared by both GEMM kernels) ----------------
#define QPHASE(KS, MH, PRE, POST)                                              \
  do {                                                                         \
    const int cx_ = (KS) ? colx1 : colx0;                                      \
    bf16x8 af0 = *(const bf16x8*)(cA + aRow0 + ((MH)*4+0)*2048 + cx_);         \
    bf16x8 af1 = *(const bf16x8*)(cA + aRow0 + ((MH)*4+1)*2048 + cx_);         \
    bf16x8 af2 = *(const bf16x8*)(cA + aRow0 + ((MH)*4+2)*2048 + cx_);         \
    bf16x8 af3 = *(const bf16x8*)(cA + aRow0 + ((MH)*4+3)*2048 + cx_);         \
    PRE                                                                        \
    BAR();                                                                     \
    LGKM0();                                                                   \
    __builtin_amdgcn_sched_barrier(0);                                         \
    __builtin_amdgcn_s_setprio(1);                                             \
    _Pragma("unroll")                                                          \
    for (int n = 0; n < 4; ++n) {                                              \
      acc[(MH)*4+0][n] = MFMA_(af0, bfr[n], acc[(MH)*4+0][n]);                 \
      acc[(MH)*4+1][n] = MFMA_(af1, bfr[n], acc[(MH)*4+1][n]);                 \
      acc[(MH)*4+2][n] = MFMA_(af2, bfr[n], acc[(MH)*4+2][n]);                 \
      acc[(MH)*4+3][n] = MFMA_(af3, bfr[n], acc[(MH)*4+3][n]);                 \
    }                                                                          \
    __builtin_amdgcn_s_setprio(0);                                             \
    POST                                                                       \
    BAR();                                                                     \
  } while (0)

// ---------------- gemm_full: A and B both via global_load_lds --------------
__global__ __launch_bounds__(512, 2)
void gemm_full(const char* __restrict__ wsA, const char* __restrict__ wsB,
               float* __restrict__ O) {
  extern __shared__ char smem[];
  char* const smA = smem;
  char* const smB = smem + 2 * LDS_TILE;

  const int bid = (int)blockIdx.x;
  const int swz = (bid & 7) * 128 + (bid >> 3);   // 1024 blocks, bijective
  const int jt = swz & 3;
  const int it = (swz >> 2) & 31;
  const int g  = swz >> 7;

  const int n0 = it * BM;
  const int c0 = jt * BN;

  const int tid  = (int)threadIdx.x;
  const int lane = tid & 63;
  const int wid  = tid >> 6;
  const int wr   = wid >> 2;
  const int wc   = wid & 3;

  const char* AgT = wsA + (size_t)((g * ITN + it) * NKT) * LDS_TILE;
  const char* BgT = wsB + (size_t)((g * JTN + jt) * NKT) * LDS_TILE;
  const int bOff = tid * 16;               // 512 thr * 16 B -> 8 KiB per pass

  const int fr = lane & 15;
  const int fq = lane >> 4;
  const int swzm  = (fr & 7) << 4;
  const int colx0 = (fq * 16) ^ swzm;
  const int colx1 = (64 + fq * 16) ^ swzm;
  const int aRow0 = (wr * 128 + fr) * ROWB;
  const int bRow0 = (wc * 64  + fr) * ROWB;

  f32x4 acc[8][4];
#pragma unroll
  for (int m = 0; m < 8; ++m)
#pragma unroll
    for (int n = 0; n < 4; ++n) acc[m][n] = (f32x4){0.f, 0.f, 0.f, 0.f};

  // ---- prologue: DMA tile 0 into buffer 0
#pragma unroll
  for (int p = 0; p < 4; ++p) {
    glds16(AgT + bOff + p * 8192, smA + bOff + p * 8192);
    glds16(BgT + bOff + p * 8192, smB + bOff + p * 8192);
  }
  VM0();
  BAR();

#pragma unroll 2
  for (int t = 0; t < NKT; ++t) {
    char* const cA = smA + (t & 1) * LDS_TILE;
    char* const cB = smB + (t & 1) * LDS_TILE;
    char* const nA = smA + ((t & 1) ^ 1) * LDS_TILE;
    char* const nB = smB + ((t & 1) ^ 1) * LDS_TILE;
    const bool stage = (t + 1) < NKT;

    bf16x8 bfr[4];
#pragma unroll
    for (int n = 0; n < 4; ++n)
      bfr[n] = *(const bf16x8*)(cB + bRow0 + n * 2048 + colx0);

    // P0: issue next-tile DMA (A+B, 8 glds16) -> in flight ~4 phases
    QPHASE(0, 0,
      { if (stage) {
          const char* An = AgT + (size_t)(t + 1) * LDS_TILE;
          const char* Bn = BgT + (size_t)(t + 1) * LDS_TILE;
          _Pragma("unroll")
          for (int p = 0; p < 4; ++p) {
            glds16(An + bOff + p * 8192, nA + bOff + p * 8192);
            glds16(Bn + bOff + p * 8192, nB + bOff + p * 8192);
          }
        } },
      { });

    QPHASE(0, 1, { }, { });

    // P2: reload B fragments for k-subtile 1
    QPHASE(1, 0,
      { _Pragma("unroll")
        for (int n = 0; n < 4; ++n)
          bfr[n] = *(const bf16x8*)(cB + bRow0 + n * 2048 + colx1);
      },
      { });

    // P3: drain this tile's DMA (issued 4 phases ago -> cheap), publish
    QPHASE(1, 1, { },
      { if (stage) { VM0(); } });
  }

  // ---- epilogue: C/D layout col = lane&15, row = (lane>>4)*4 + reg (m89)
#pragma unroll
  for (int m = 0; m < 8; ++m) {
#pragma unroll
    for (int r = 0; r < 4; ++r) {
      const int row = wr * 128 + m * 16 + fq * 4 + r;
      float* orow = O + ((size_t)(n0 + row) * NG + g) * DOUT + c0 + wc * 64;
#pragma unroll
      for (int n = 0; n < 4; ++n) {
        orow[n * 16 + fr] = acc[m][n][r];
      }
    }
  }
}

// ---------------- round-4 kernel (fallback paths) --------------------------
template <bool WSB>
__global__ __launch_bounds__(512, 2)
void grouped_gemm_8p(const float* __restrict__ X,
                     const float* __restrict__ W,
                     const char* __restrict__ wsB,
                     float* __restrict__ O) {
  extern __shared__ char smem[];
  char* const smA = smem;
  char* const smB = smem + 2 * LDS_TILE;

  const int bid = (int)blockIdx.x;
  const int swz = (bid & 7) * 128 + (bid >> 3);
  const int jt = swz & 3;
  const int it = (swz >> 2) & 31;
  const int g  = swz >> 7;

  const int n0 = it * BM;
  const int c0 = jt * BN;

  const int tid  = (int)threadIdx.x;
  const int lane = tid & 63;
  const int wid  = tid >> 6;
  const int wr   = wid >> 2;
  const int wc   = wid & 3;

  const int s_lane = tid & 15;
  const int s_row  = tid >> 4;

  const float* Ag = X + ((size_t)(n0 + s_row) * NG + g) * DIN + s_lane * 4;
  constexpr size_t ASTR = (size_t)32 * NG * DIN;

  const float* Bg = W + (size_t)g * DOUT * DIN + (size_t)(c0 + s_row) * DIN
                      + s_lane * 4;
  constexpr size_t BSTR = (size_t)32 * DIN;

  const char* BgT = wsB + ((size_t)(g * JTN + jt) * NKT) * LDS_TILE;
  const int bOff = tid * 16;

  const int wb0 = s_row * ROWB + ((s_lane * 8) ^ ((s_row & 7) << 4));

  const int fr = lane & 15;
  const int fq = lane >> 4;
  const int swzm  = (fr & 7) << 4;
  const int colx0 = (fq * 16) ^ swzm;
  const int colx1 = (64 + fq * 16) ^ swzm;
  const int aRow0 = (wr * 128 + fr) * ROWB;
  const int bRow0 = (wc * 64  + fr) * ROWB;

  f32x4 aS[8], bS[8];
  f32x4 acc[8][4];
#pragma unroll
  for (int m = 0; m < 8; ++m)
#pragma unroll
    for (int n = 0; n < 4; ++n) acc[m][n] = (f32x4){0.f, 0.f, 0.f, 0.f};

  if (WSB) {
#pragma unroll
    for (int p = 0; p < 4; ++p)
      glds16(BgT + bOff + p * 8192, smB + bOff + p * 8192);
  } else {
#pragma unroll
    for (int p = 0; p < 8; ++p) bS[p] = *(const f32x4*)(Bg + p * BSTR);
  }
#pragma unroll
  for (int p = 0; p < 8; ++p) aS[p] = *(const f32x4*)(Ag + p * ASTR);
#pragma unroll
  for (int p = 0; p < 8; ++p)
    *(uint2*)(smA + wb0 + p * 4096) = pack_bf16x4(aS[p]);
  if (!WSB) {
#pragma unroll
    for (int p = 0; p < 8; ++p)
      *(uint2*)(smB + wb0 + p * 4096) = pack_bf16x4(bS[p]);
  }
  VM0();
  LGKM0();
  BAR();

#pragma unroll 2
  for (int t = 0; t < NKT; ++t) {
    char* const cA = smA + (t & 1) * LDS_TILE;
    char* const cB = smB + (t & 1) * LDS_TILE;
    char* const nA = smA + ((t & 1) ^ 1) * LDS_TILE;
    char* const nB = smB + ((t & 1) ^ 1) * LDS_TILE;
    const bool stage = (t + 1) < NKT;

    bf16x8 bfr[4];
#pragma unroll
    for (int n = 0; n < 4; ++n)
      bfr[n] = *(const bf16x8*)(cB + bRow0 + n * 2048 + colx0);

    QPHASE(0, 0,
      { if (stage) {
          const float* An = Ag + (size_t)(t + 1) * BK;
          _Pragma("unroll")
          for (int p = 0; p < 8; ++p) aS[p] = *(const f32x4*)(An + p * ASTR);
          if (WSB) {
            const char* Bn = BgT + (size_t)(t + 1) * LDS_TILE;
            _Pragma("unroll")
            for (int p = 0; p < 4; ++p)
              glds16(Bn + bOff + p * 8192, nB + bOff + p * 8192);
          }
        } },
      { });

    QPHASE(0, 1,
      { if (!WSB && stage) {
          const float* Bn = Bg + (size_t)(t + 1) * BK;
          _Pragma("unroll")
          for (int p = 0; p < 8; ++p) bS[p] = *(const f32x4*)(Bn + p * BSTR);
        } },
      { });

    QPHASE(1, 0,
      { _Pragma("unroll")
        for (int n = 0; n < 4; ++n)
          bfr[n] = *(const bf16x8*)(cB + bRow0 + n * 2048 + colx1);
      },
      { if (stage) {
          _Pragma("unroll")
          for (int p = 0; p < 8; ++p)
            *(uint2*)(nA + wb0 + p * 4096) = pack_bf16x4(aS[p]);
        } });

    QPHASE(1, 1, { },
      { if (!WSB && stage) {
          _Pragma("unroll")
          for (int p = 0; p < 8; ++p)
            *(uint2*)(nB + wb0 + p * 4096) = pack_bf16x4(bS[p]);
        }
        LGKM0();
        if (WSB && stage) { VM0(); } });
  }

#pragma unroll
  for (int m = 0; m < 8; ++m) {
#pragma unroll
    for (int r = 0; r < 4; ++r) {
      const int row = wr * 128 + m * 16 + fq * 4 + r;
      float* orow = O + ((size_t)(n0 + row) * NG + g) * DOUT + c0 + wc * 64;
#pragma unroll
      for (int n = 0; n < 4; ++n) {
        orow[n * 16 + fr] = acc[m][n][r];
      }
    }
  }
}

} // namespace

extern "C" void kernel_launch(void* const* d_in, const int* in_sizes, int n_in,
                              void* d_out, int out_size, void* d_ws, size_t ws_size,
                              hipStream_t stream) {
  (void)n_in; (void)out_size;
  const float* X = (const float*)d_in[0];
  const float* W = (const float*)d_in[1];
  float* O = (float*)d_out;

  const int tokens_total = in_sizes[0] / DIN;            // 65536
  const int ntok_per_g   = tokens_total / NG;            // 8192
  const int grid = NG * (ntok_per_g / BM) * (DOUT / BN); // 1024

  if (ws_size >= WSF_BYTES) {
    char* wsA = (char*)d_ws;
    char* wsB = (char*)d_ws + WSA_BYTES;
    cvt_x_kernel<<<dim3((int)(WSA_BYTES / 16 / 256)), dim3(256), 0, stream>>>(X, wsA);
    cvt_w_kernel<<<dim3((int)(WSB_BYTES / 4 / 256)), dim3(256), 0, stream>>>(W, wsB);
    (void)hipFuncSetAttribute((const void*)gemm_full,
                              hipFuncAttributeMaxDynamicSharedMemorySize,
                              LDS_BYTES);
    gemm_full<<<dim3(grid), dim3(512), LDS_BYTES, stream>>>(wsA, wsB, O);
  } else if (ws_size >= WSB_BYTES) {
    cvt_w_kernel<<<dim3((int)(WSB_BYTES / 4 / 256)), dim3(256), 0, stream>>>(
        W, (char*)d_ws);
    (void)hipFuncSetAttribute((const void*)grouped_gemm_8p<true>,
                              hipFuncAttributeMaxDynamicSharedMemorySize,
                              LDS_BYTES);
    grouped_gemm_8p<true><<<dim3(grid), dim3(512), LDS_BYTES, stream>>>(
        X, W, (const char*)d_ws, O);
  } else {
    (void)hipFuncSetAttribute((const void*)grouped_gemm_8p<false>,
                              hipFuncAttributeMaxDynamicSharedMemorySize,
                              LDS_BYTES);
    grouped_gemm_8p<false><<<dim3(grid), dim3(512), LDS_BYTES, stream>>>(
        X, W, nullptr, O);
  }
}

// Round 7
// 224.254 us; speedup vs baseline: 2.7936x; 1.2205x over previous
//
#include <hip/hip_runtime.h>
#include <hip/hip_bf16.h>

// Grouped GEMM: out[n,g,k] = sum_d x[n*8+g, d] * W[g, k, d]
// Round 7: fused-A structure, 2 blocks/CU.
//  - cvt_w (~8us): W f32 -> bf16 image, tiles [g][jt:4][kt:32] of [256r][32k],
//    granule (r,w) holds src k-chunk (w ^ (r&3))  (swizzle baked in).
//  - gemm: BM=128 BN=256 BK=32, 8 waves (2Mx4N, 64x64/wave, acc 4x4).
//    A staged as RAW F32 via global_load_lds with per-lane pre-swizzled
//    source (rule #21), converted to bf16 at fragment-read (4 cvt_pk/frag).
//    B via global_load_lds from image. LDS 64 KiB -> 2 blocks/CU; regs <=128
//    -> 4 waves/SIMD. ONE vmcnt(0)+barrier per K-tile; no phase barriers.

namespace {

constexpr int NG   = 8;
constexpr int DIN  = 1024;
constexpr int DOUT = 1024;
constexpr int BM   = 128;
constexpr int BN   = 256;
constexpr int BK   = 32;
constexpr int NKT  = DIN / BK;            // 32
constexpr int AROWB = BK * 4;             // 128 B per A row (f32)
constexpr int BROWB = BK * 2;             // 64 B per B row (bf16)
constexpr int ATILE = BM * AROWB;         // 16 KiB
constexpr int BTILE = BN * BROWB;         // 16 KiB
constexpr int LDS_BYTES = 2 * ATILE + 2 * BTILE;   // 64 KiB
constexpr int JTN  = DOUT / BN;           // 4
constexpr size_t WSB_BYTES = (size_t)NG * JTN * NKT * BTILE;  // 16.78 MB

typedef __attribute__((ext_vector_type(8))) short bf16x8;
typedef __attribute__((ext_vector_type(4))) float f32x4;

__device__ __forceinline__ bf16x8 pack_bf16x8v(f32x4 lo, f32x4 hi) {
  union { __hip_bfloat162 h2[4]; bf16x8 v; } p;
  p.h2[0] = __float22bfloat162_rn(make_float2(lo.x, lo.y));
  p.h2[1] = __float22bfloat162_rn(make_float2(lo.z, lo.w));
  p.h2[2] = __float22bfloat162_rn(make_float2(hi.x, hi.y));
  p.h2[3] = __float22bfloat162_rn(make_float2(hi.z, hi.w));
  return p.v;
}

__device__ __forceinline__ void glds16(const void* g, void* l) {
  __builtin_amdgcn_global_load_lds(
      (const __attribute__((address_space(1))) unsigned int*)g,
      (__attribute__((address_space(3))) unsigned int*)l, 16, 0, 0);
}

#define FENCE() asm volatile("" ::: "memory")
#define BAR()   do { FENCE(); __builtin_amdgcn_s_barrier(); FENCE(); } while (0)
#define LGKM0() asm volatile("s_waitcnt lgkmcnt(0)" ::: "memory")
#define VM0()   asm volatile("s_waitcnt vmcnt(0)" ::: "memory")
#define MFMA_(a, b, c) __builtin_amdgcn_mfma_f32_16x16x32_bf16((a), (b), (c), 0, 0, 0)

// ---------------- cvt_w: W f32 -> bf16 swizzled B-image --------------------
// one thread per 16-B dest granule. tile = (g*4+jt)*32+kt, 1024 granules/tile.
__global__ __launch_bounds__(256)
void cvt_w_kernel(const float* __restrict__ W, char* __restrict__ wsB) {
  const int q    = (int)blockIdx.x * 256 + (int)threadIdx.x;
  const int tile = q >> 10;
  const int r    = (q & 1023) >> 2;    // B-tile row (out-col within panel)
  const int w    = q & 3;              // dest granule in row
  const int g    = tile >> 7;
  const int jt   = (tile >> 5) & 3;
  const int kt   = tile & 31;

  const float* src = W + (size_t)(g * DOUT + jt * BN + r) * DIN
                       + kt * BK + ((w ^ (r & 3)) * 8);
  f32x4 lo = *(const f32x4*)(src);
  f32x4 hi = *(const f32x4*)(src + 4);
  *(bf16x8*)(wsB + (size_t)q * 16) = pack_bf16x8v(lo, hi);
}

// ---------------- gemm ------------------------------------------------------
template <bool WSB>
__global__ __launch_bounds__(512, 4)
void gemm_k(const float* __restrict__ X, const float* __restrict__ W,
            const char* __restrict__ wsB, float* __restrict__ O) {
  extern __shared__ char smem[];
  char* const smA = smem;                 // [2][16 KiB] f32, swizzled
  char* const smB = smem + 2 * ATILE;     // [2][16 KiB] bf16, swizzled

  // ---- block mapping: group == XCD (2048 blocks, 256/XCD), bijective
  const int bid = (int)blockIdx.x;
  const int swz = (bid & 7) * 256 + (bid >> 3);
  const int jt = swz & 3;                 // col panel [0,4) fastest (A reuse)
  const int it = (swz >> 2) & 63;         // row tile  [0,64)
  const int g  = swz >> 8;                // group     [0,8)  == XCD

  const int n0 = it * BM;
  const int c0 = jt * BN;

  const int tid  = (int)threadIdx.x;
  const int lane = tid & 63;
  const int wid  = tid >> 6;              // 8 waves: 2(M) x 4(N)
  const int wr   = wid >> 2;
  const int wc   = wid & 3;
  const int fr   = lane & 15;
  const int fq   = lane >> 4;

  // ---- A staging: dest (p*64 + tid>>3) row, granule tid&7; source chunk
  // swizzled by (row&7) so linear DMA dest == swizzled LDS image.
  const int aR = tid >> 3;                // row for p=0 (p=1 adds 64; &7 same)
  const int aw = (tid & 7) ^ (aR & 7);    // source 16-B chunk
  const char* aSrc0 = (const char*)X
      + ((size_t)(n0 + aR) * NG + g) * (DIN * 4) + aw * 16;
  const char* aSrc1 = aSrc0 + (size_t)64 * NG * DIN * 4;

  // ---- B staging: image stream (WSB) or raw W (fallback)
  const char* BgT = wsB + (size_t)((g * JTN + jt) * NKT) * BTILE;
  // fallback: thread handles rows s_r, s_r+128; src k-chunk s_l*8 f32
  const int s_l = tid & 3;
  const int s_r = tid >> 2;
  const float* Bg = W + (size_t)g * DOUT * DIN + (size_t)(c0 + s_r) * DIN
                      + s_l * 8;
  const int bw0 = s_r * BROWB + ((s_l ^ (s_r & 3)) * 16);

  // ---- fragment LDS addressing (XOR involutions match staging side)
  const int gA0   = (2 * fq) ^ (fr & 7);
  const int aoff0 = (wr * 64 + fr) * AROWB + gA0 * 16;
  const int aoff1 = (wr * 64 + fr) * AROWB + (gA0 ^ 1) * 16;
  const int boff  = (wc * 64 + fr) * BROWB + ((fq ^ (fr & 3)) * 16);

  f32x4 acc[4][4];
#pragma unroll
  for (int m = 0; m < 4; ++m)
#pragma unroll
    for (int n = 0; n < 4; ++n) acc[m][n] = (f32x4){0.f, 0.f, 0.f, 0.f};

  // ---- prologue: stage tile 0 into buffer 0
  glds16(aSrc0, smA + tid * 16);
  glds16(aSrc1, smA + 8192 + tid * 16);
  if (WSB) {
    glds16(BgT + tid * 16, smB + tid * 16);
    glds16(BgT + 8192 + tid * 16, smB + 8192 + tid * 16);
  } else {
    f32x4 b0 = *(const f32x4*)(Bg);
    f32x4 b1 = *(const f32x4*)(Bg + 4);
    f32x4 b2 = *(const f32x4*)(Bg + (size_t)128 * DIN);
    f32x4 b3 = *(const f32x4*)(Bg + (size_t)128 * DIN + 4);
    *(bf16x8*)(smB + bw0)        = pack_bf16x8v(b0, b1);
    *(bf16x8*)(smB + 8192 + bw0) = pack_bf16x8v(b2, b3);
    LGKM0();
  }
  VM0();
  BAR();

  for (int t = 0; t < NKT; ++t) {
    char* const cA = smA + (t & 1) * ATILE;
    char* const cB = smB + (t & 1) * BTILE;
    char* const nA = smA + ((t & 1) ^ 1) * ATILE;
    char* const nB = smB + ((t & 1) ^ 1) * BTILE;
    const bool stage = (t + 1) < NKT;

    // issue next-tile staging first (cover = one K-tile of MFMA)
    f32x4 bS0, bS1, bS2, bS3;
    if (stage) {
      glds16(aSrc0 + (size_t)(t + 1) * (BK * 4), nA + tid * 16);
      glds16(aSrc1 + (size_t)(t + 1) * (BK * 4), nA + 8192 + tid * 16);
      if (WSB) {
        const char* Bn = BgT + (size_t)(t + 1) * BTILE;
        glds16(Bn + tid * 16, nB + tid * 16);
        glds16(Bn + 8192 + tid * 16, nB + 8192 + tid * 16);
      } else {
        const float* Bn = Bg + (size_t)(t + 1) * BK;
        bS0 = *(const f32x4*)(Bn);
        bS1 = *(const f32x4*)(Bn + 4);
        bS2 = *(const f32x4*)(Bn + (size_t)128 * DIN);
        bS3 = *(const f32x4*)(Bn + (size_t)128 * DIN + 4);
      }
    }

    // B fragments (bf16, 4 x ds_read_b128)
    bf16x8 bfr[4];
#pragma unroll
    for (int n = 0; n < 4; ++n)
      bfr[n] = *(const bf16x8*)(cB + boff + n * 1024);

    // A fragments: raw f32 from LDS -> cvt_pk -> MFMA
    __builtin_amdgcn_s_setprio(1);
#pragma unroll
    for (int m = 0; m < 4; ++m) {
      f32x4 lo = *(const f32x4*)(cA + aoff0 + m * 2048);
      f32x4 hi = *(const f32x4*)(cA + aoff1 + m * 2048);
      bf16x8 am = pack_bf16x8v(lo, hi);
#pragma unroll
      for (int n = 0; n < 4; ++n)
        acc[m][n] = MFMA_(am, bfr[n], acc[m][n]);
    }
    __builtin_amdgcn_s_setprio(0);

    if (!WSB && stage) {
      *(bf16x8*)(nB + bw0)        = pack_bf16x8v(bS0, bS1);
      *(bf16x8*)(nB + 8192 + bw0) = pack_bf16x8v(bS2, bS3);
      LGKM0();
    }
    if (stage) { VM0(); BAR(); }
  }

  // ---- epilogue: C/D layout col = lane&15, row = (lane>>4)*4 + reg (m89)
#pragma unroll
  for (int m = 0; m < 4; ++m) {
#pragma unroll
    for (int r = 0; r < 4; ++r) {
      const int row = wr * 64 + m * 16 + fq * 4 + r;
      float* orow = O + ((size_t)(n0 + row) * NG + g) * DOUT + c0 + wc * 64;
#pragma unroll
      for (int n = 0; n < 4; ++n) {
        orow[n * 16 + fr] = acc[m][n][r];
      }
    }
  }
}

} // namespace

extern "C" void kernel_launch(void* const* d_in, const int* in_sizes, int n_in,
                              void* d_out, int out_size, void* d_ws, size_t ws_size,
                              hipStream_t stream) {
  (void)n_in; (void)out_size;
  const float* X = (const float*)d_in[0];
  const float* W = (const float*)d_in[1];
  float* O = (float*)d_out;

  const int tokens_total = in_sizes[0] / DIN;            // 65536
  const int ntok_per_g   = tokens_total / NG;            // 8192
  const int grid = NG * (ntok_per_g / BM) * (DOUT / BN); // 2048

  if (ws_size >= WSB_BYTES) {
    const int cvt_grid = (int)(WSB_BYTES / 16 / 256);    // 4096
    cvt_w_kernel<<<dim3(cvt_grid), dim3(256), 0, stream>>>(W, (char*)d_ws);
    (void)hipFuncSetAttribute((const void*)gemm_k<true>,
                              hipFuncAttributeMaxDynamicSharedMemorySize,
                              LDS_BYTES);
    gemm_k<true><<<dim3(grid), dim3(512), LDS_BYTES, stream>>>(
        X, W, (const char*)d_ws, O);
  } else {
    (void)hipFuncSetAttribute((const void*)gemm_k<false>,
                              hipFuncAttributeMaxDynamicSharedMemorySize,
                              LDS_BYTES);
    gemm_k<false><<<dim3(grid), dim3(512), LDS_BYTES, stream>>>(
        X, W, nullptr, O);
  }
}